// Round 2
// baseline (2566.870 us; speedup 1.0000x reference)
//
#include <hip/hip_runtime.h>
#include <math.h>

#define NTAU 82
#define TMIN 28
#define S_TOT 5617
#define TF 6000
#define BATCH 4
#define WMAX 28
#define AP 84            // A/fb row pitch: 82 + 2 pad; 336B -> float4-aligned rows
#define NTHREADS 1024
#define NCHUNK 215
#define CHUNK_G (WMAX * AP)   // 2352 floats per chunk of A-history
#define FLAG_STRIDE 64        // one flag per 256B line
#define VSZ 1456              // max quarter V size (1449) padded
#define SENT (NCHUNK + 1)     // result sentinel flag value (216)

// ws layout (float offsets)
#define TRANS_OFF 0            // 82*82
#define BLP_OFF   8192         // 4*6000
#define NBLP_OFF  32768        // 4*6000
#define AH_OFF    57344        // 4 * 215 * 2352 A-history (exchange + backtrace)
#define FLAG_OFF  (AH_OFF + BATCH * NCHUNK * CHUNK_G)   // 16 flags x 64 ints
#define RESV_OFF  (FLAG_OFF + 16 * FLAG_STRIDE)          // 16 floats
#define RESI_OFF  (RESV_OFF + 16)                        // 16 ints

__device__ __forceinline__ int first_of(int bb) { return bb * (55 + bb) / 2; }

// block i -> column position in quarter-grouped A row layout
__device__ __forceinline__ int qpos_of(int i) {
    const int qq = i & 3, kk = i >> 2;
    const int qb = 21 * qq - ((qq == 3) ? 1 : 0);
    return qb + kk;
}

__device__ __forceinline__ float logsig(float x) {
    return -(fmaxf(-x, 0.0f) + log1pf(expf(-fabsf(x))));
}

// ---------------- setup kernel 1: trans_log in fp64, cast to fp32 -------------
__global__ void k_trans(float* __restrict__ ws) {
    int i = blockIdx.x;
    int j = threadIdx.x;
    __shared__ double sh[128];
    double raw = 0.0, e = 0.0;
    double ti = 28.0 + (double)i;
    if (j < NTAU) {
        double tj = 28.0 + (double)j;
        raw = -100.0 * fabs(tj / ti - 1.0);
        e = exp(raw);
    }
    sh[j] = e;
    __syncthreads();
    for (int st = 64; st > 0; st >>= 1) {
        if (j < st) sh[j] += sh[j + st];
        __syncthreads();
    }
    double lse = log(sh[0]);
    if (j < NTAU) ws[TRANS_OFF + i * NTAU + j] = (float)(raw - lse);
}

// ---------------- setup kernel 2: emissions + zero output ---------------------
__global__ void k_emis(const float* __restrict__ logit, float* __restrict__ ws,
                       float* __restrict__ out) {
    int idx = blockIdx.x * blockDim.x + threadIdx.x;
    if (idx < BATCH * TF) {
        float x = logit[idx];
        ws[BLP_OFF + idx]  = logsig(x);
        ws[NBLP_OFF + idx] = logsig(-x);
        out[idx] = 0.0f;
    }
}

// ---------------- setup kernel 3: zero the handshake flags --------------------
__global__ void k_flags(int* __restrict__ flags) {
    int i = blockIdx.x * blockDim.x + threadIdx.x;
    if (i < 16 * FLAG_STRIDE) flags[i] = 0;
}

// ---------------- main kernel: 8 WGs, 2 antiphase quarter-streams each --------
// WG w: quarter q = w&3 of batch bx = w>>2 (stream X) AND of batch by = 2+(w>>2)
// (stream Y). Quarters = blocks j with j%4 == q (balanced V/chain load). The 4
// quarters of a batch exchange capture rows through per-chunk first-touch Ah
// buffers (champion-proven sc1-store + barrier-drain + relaxed-flag protocol);
// each stream's L3 round-trip hides under the OTHER stream's compute phases.
// All emission chains exact-sequential; max-plus single-add+max => bit-exact.
__global__ __attribute__((amdgpu_flat_work_group_size(NTHREADS, NTHREADS),
                          amdgpu_waves_per_eu(4, 4),
                          amdgpu_num_vgpr(128)))
void k_viterbi(const float* __restrict__ logit,
               const float* __restrict__ transg,
               const float* __restrict__ blp_all,
               const float* __restrict__ nblp_all,
               float* __restrict__ Ah_all,
               int*   __restrict__ flags,
               float* __restrict__ resv,
               int*   __restrict__ resi,
               float* __restrict__ out) {
    const int tid = threadIdx.x;
    const int w   = blockIdx.x;
    const int q   = w & 3;
    const int bx  = w >> 2;        // batch 0/1
    const int by  = 2 + (w >> 2);  // batch 2/3
    const int nq  = (q < 2) ? 21 : 20;
    const int qbase = 21 * q - ((q == 3) ? 1 : 0);

    const float* blpX  = blp_all  + bx * TF;
    const float* nblpX = nblp_all + bx * TF;
    const float* blpY  = blp_all  + by * TF;
    const float* nblpY = nblp_all + by * TF;
    float* AhX = Ah_all + (size_t)bx * (NCHUNK * CHUNK_G);
    float* AhY = Ah_all + (size_t)by * (NCHUNK * CHUNK_G);

    __shared__ float V_X[VSZ];
    __shared__ float V_Y[VSZ];
    __shared__ __align__(16) float A[CHUNK_G];    // shared between streams (disjoint windows)
    __shared__ __align__(16) float fb[CHUNK_G];
    __shared__ __align__(16) float wnbX[4][WMAX], wbX[4][WMAX];
    __shared__ __align__(16) float wnbY[4][WMAX], wbY[4][WMAX];
    __shared__ float wv[16];
    __shared__ int   wi[16];
    __shared__ int   sstate;

    // ---- ph2 mapping: quad lanes = iseg (i-window); 21 j-cols; 12 row-groups --
    const int iseg = tid & 3;
    const int jc   = (tid >> 2) % 21;
    const int rg   = tid / 84;            // quads never straddle rg boundaries
    const bool p2act = (tid < 1008) && (jc < nq);
    const int ib = iseg * 20;             // i-window [ib, ib+22); 16B-aligned
    const int jown = q + 4 * jc;

    float tr[22];
#pragma unroll
    for (int k = 0; k < 22; ++k) tr[k] = -1.0e30f;
    if (p2act) {
#pragma unroll
        for (int k = 0; k < 22; ++k) {
            const int p  = ib + k;
            const int qi = (p < 21) ? 0 : (p < 42) ? 1 : (p < 62) ? 2 : 3;
            const int qb = 21 * qi - ((qi == 3) ? 1 : 0);
            const int i  = qi + 4 * (p - qb);
            tr[k] = transg[i * NTAU + jown];
        }
    }

    // ---- capture slots: slot = ro*nq + kb (one per thread) --------------------
    const bool cact = (tid < WMAX * nq);
    const int ro  = cact ? (tid / nq) : 0;
    const int kb  = cact ? (tid % nq) : 0;
    const int tauC  = TMIN + q + 4 * kb;
    const int lfoC  = kb * (TMIN + q) + 2 * kb * (kb - 1);
    const int coff  = ro * AP + qbase + kb;
    const int climC = lfoC + tauC;
    int cvaX = lfoC + ro;
    int cvaY = lfoC + ro;

    // ---- nonreset slots: flat f over NN (one per thread) ----------------------
    const int NN = nq * q + 2 * nq * (nq - 1);
    const bool nact = (tid < NN);
    int nva, nlim, ntau;
    {
        const int f = nact ? tid : 0;
        int lo = 0, hi = nq - 1;
        while (lo < hi) { int mid = (lo + hi + 1) >> 1;
                          if (mid * q + 2 * mid * (mid - 1) <= f) lo = mid; else hi = mid - 1; }
        const int m    = f - (lo * q + 2 * lo * (lo - 1));
        const int nlfo = lo * (TMIN + q) + 2 * lo * (lo - 1);
        ntau = TMIN + q + 4 * lo;
        nva  = nlfo + TMIN + m;
        nlim = nlfo + ntau;
    }

    // ---- V init (both streams) ------------------------------------------------
    const int sv = nq * (TMIN + q) + 2 * nq * (nq - 1);
    const float logS = (float)log((double)S_TOT);
    {
        const float b0x = blpX[0], n0x = nblpX[0];
        const float b0y = blpY[0], n0y = nblpY[0];
        for (int g = tid; g < sv; g += NTHREADS) {
            int lo = 0, hi = nq - 1;
            while (lo < hi) { int mid = (lo + hi + 1) >> 1;
                              if (mid * (TMIN + q) + 2 * mid * (mid - 1) <= g) lo = mid; else hi = mid - 1; }
            const int r   = g - (lo * (TMIN + q) + 2 * lo * (lo - 1));
            const int tau = TMIN + q + 4 * lo;
            V_X[g] = ((r == tau - 1) ? b0x : n0x) - logS;
            V_Y[g] = ((r == tau - 1) ? b0y : n0y) - logS;
        }
    }

    auto winX = [&](int cc) { if (cc < NCHUNK && tid < WMAX) {
        const int gt = 1 + cc * WMAX + tid;
        wnbX[cc & 3][tid] = (gt < TF) ? nblpX[gt] : 0.0f;
        wbX [cc & 3][tid] = (gt < TF) ? blpX[gt]  : 0.0f; } };
    auto winY = [&](int cc) { if (cc < NCHUNK && tid < WMAX) {
        const int gt = 1 + cc * WMAX + tid;
        wnbY[cc & 3][tid] = (gt < TF) ? nblpY[gt] : 0.0f;
        wbY [cc & 3][tid] = (gt < TF) ? blpY[gt]  : 0.0f; } };
    winX(0); winX(1); winY(0); winY(1);
    __syncthreads();

    // ---- per-wave poll of the 3 partner quarters ------------------------------
    auto pollq = [&](int bbase, int need) {
        const int* p1 = flags + (bbase + ((q + 1) & 3)) * FLAG_STRIDE;
        const int* p2 = flags + (bbase + ((q + 2) & 3)) * FLAG_STRIDE;
        const int* p3 = flags + (bbase + ((q + 3) & 3)) * FLAG_STRIDE;
        int guard = 0;
        while (true) {
            const int f1 = __hip_atomic_load(p1, __ATOMIC_RELAXED, __HIP_MEMORY_SCOPE_AGENT);
            const int f2 = __hip_atomic_load(p2, __ATOMIC_RELAXED, __HIP_MEMORY_SCOPE_AGENT);
            const int f3 = __hip_atomic_load(p3, __ATOMIC_RELAXED, __HIP_MEMORY_SCOPE_AGENT);
            if (f1 >= need && f2 >= need && f3 >= need) break;
            __builtin_amdgcn_s_sleep(1);
            if (++guard > (1 << 24)) break;   // hang guard -> visible failure
        }
        __builtin_amdgcn_fence(__ATOMIC_ACQUIRE, "agent");  // pin import loads after poll
    };

    auto ph2 = [&]() {
        if (p2act) {
#pragma unroll
            for (int u = 0; u < 3; ++u) {
                const int tl = rg + 12 * u;
                if (tl < WMAX) {
                    const float* ar = &A[tl * AP + ib];
                    const float4 a0 = ((const float4*)ar)[0];
                    const float4 a1 = ((const float4*)ar)[1];
                    const float4 a2 = ((const float4*)ar)[2];
                    const float4 a3 = ((const float4*)ar)[3];
                    const float4 a4 = ((const float4*)ar)[4];
                    const float  e0 = ar[20], e1 = ar[21];
                    float m0 = -INFINITY, m1 = -INFINITY;
                    m0 = fmaxf(m0, a0.x + tr[0]);  m1 = fmaxf(m1, a0.y + tr[1]);
                    m0 = fmaxf(m0, a0.z + tr[2]);  m1 = fmaxf(m1, a0.w + tr[3]);
                    m0 = fmaxf(m0, a1.x + tr[4]);  m1 = fmaxf(m1, a1.y + tr[5]);
                    m0 = fmaxf(m0, a1.z + tr[6]);  m1 = fmaxf(m1, a1.w + tr[7]);
                    m0 = fmaxf(m0, a2.x + tr[8]);  m1 = fmaxf(m1, a2.y + tr[9]);
                    m0 = fmaxf(m0, a2.z + tr[10]); m1 = fmaxf(m1, a2.w + tr[11]);
                    m0 = fmaxf(m0, a3.x + tr[12]); m1 = fmaxf(m1, a3.y + tr[13]);
                    m0 = fmaxf(m0, a3.z + tr[14]); m1 = fmaxf(m1, a3.w + tr[15]);
                    m0 = fmaxf(m0, a4.x + tr[16]); m1 = fmaxf(m1, a4.y + tr[17]);
                    m0 = fmaxf(m0, a4.z + tr[18]); m1 = fmaxf(m1, a4.w + tr[19]);
                    m0 = fmaxf(m0, e0 + tr[20]);   m1 = fmaxf(m1, e1 + tr[21]);
                    float m = fmaxf(m0, m1);
                    m = fmaxf(m, __shfl_xor(m, 1));
                    m = fmaxf(m, __shfl_xor(m, 2));
                    if (iseg == 0) fb[tl * AP + qbase + jc] = m;
                }
            }
        }
    };

    // ---- prologue: publish Y.capture(0) so everyone can import at c=0 --------
    float cvX = 0.0f, cvY = 0.0f;
    {
        float s = V_Y[cvaY];
        for (int tt = 0; tt < ro; ++tt) s += wnbY[0][tt];
        cvY = s;
        if (cact)
            __hip_atomic_store(&AhY[coff], s, __ATOMIC_RELAXED, __HIP_MEMORY_SCOPE_AGENT);
    }
    __syncthreads();   // drain prologue publishes
    if (tid == 0)
        __hip_atomic_store(&flags[(by * 4 + q) * FLAG_STRIDE], 1,
                           __ATOMIC_RELAXED, __HIP_MEMORY_SCOPE_AGENT);

    const int irow = tid / 21, ic4 = tid % 21;   // import mapping (tid<588)

    for (int c = 0; c < NCHUNK; ++c) {
        const int buf = c & 3;
        float* AhXc = AhX + (size_t)c * CHUNK_G;
        float* AhYc = AhY + (size_t)c * CHUNK_G;
        float4 v4 = make_float4(0.f, 0.f, 0.f, 0.f);

        // ---- poll Y(c) partners; issue Y import; X.capture(c)+publish ----
        pollq(by * 4, c + 1);
        if (tid < 588) v4 = *(const float4*)&AhYc[irow * AP + ic4 * 4];
        {
            float s = V_X[cvaX];
            for (int tt = 0; tt < ro; ++tt) s += wnbX[buf][tt];
            cvX = s;
            if (cact)
                __hip_atomic_store(&AhXc[coff], s, __ATOMIC_RELAXED, __HIP_MEMORY_SCOPE_AGENT);
        }
        winX(c + 2);
        __syncthreads();                                     // B1 (drains X publish)
        if (tid == 0)
            __hip_atomic_store(&flags[(bx * 4 + q) * FLAG_STRIDE], c + 1,
                               __ATOMIC_RELAXED, __HIP_MEMORY_SCOPE_AGENT);

        // ---- stage Y import into A; Y.nonreset ----
        if (tid < 588) *(float4*)&A[irow * AP + ic4 * 4] = v4;
        {
            float x = V_Y[nva];
#pragma unroll
            for (int tt = 0; tt < WMAX; ++tt) x += wnbY[buf][tt];
            if (nact) V_Y[nva] = x;
        }
        winY(c + 2);
        __syncthreads();                                     // B2 (A = Y rows)

        ph2();                                               // Y from_beat
        __syncthreads();                                     // B3 (fb = Y)

        // ---- Y.suffix ----
        if (cact) {
            float e = fb[coff] + wbY[buf][ro];
            for (int tt = ro + 1; tt < WMAX; ++tt) e += wnbY[buf][tt];
            const bool keepC = (c == NCHUNK - 1) && (ro >= 7);
            V_Y[cvaY] = keepC ? cvY : e;
        }
        cvaY += WMAX; if (cvaY >= climC) cvaY -= tauC;
        __syncthreads();                                     // B4 (V_Y complete)

        // ---- poll X(c) partners; issue X import; Y.capture(c+1)+publish ----
        pollq(bx * 4, c + 1);
        if (tid < 588) v4 = *(const float4*)&AhXc[irow * AP + ic4 * 4];
        if (c + 1 < NCHUNK) {
            float s = V_Y[cvaY];
            for (int tt = 0; tt < ro; ++tt) s += wnbY[(c + 1) & 3][tt];
            cvY = s;
            if (cact)
                __hip_atomic_store(&AhY[(size_t)(c + 1) * CHUNK_G + coff], s,
                                   __ATOMIC_RELAXED, __HIP_MEMORY_SCOPE_AGENT);
        }
        __syncthreads();                                     // B5 (drains Y publish)
        if (tid == 0 && c + 1 < NCHUNK)
            __hip_atomic_store(&flags[(by * 4 + q) * FLAG_STRIDE], c + 2,
                               __ATOMIC_RELAXED, __HIP_MEMORY_SCOPE_AGENT);

        // ---- stage X import into A; X.nonreset ----
        if (tid < 588) *(float4*)&A[irow * AP + ic4 * 4] = v4;
        {
            float x = V_X[nva];
#pragma unroll
            for (int tt = 0; tt < WMAX; ++tt) x += wnbX[buf][tt];
            if (nact) V_X[nva] = x;
        }
        nva += WMAX; if (nva >= nlim) nva -= ntau;
        __syncthreads();                                     // B6 (A = X rows)

        ph2();                                               // X from_beat
        __syncthreads();                                     // B7 (fb = X)

        // ---- X.suffix ----
        if (cact) {
            float e = fb[coff] + wbX[buf][ro];
            for (int tt = ro + 1; tt < WMAX; ++tt) e += wnbX[buf][tt];
            const bool keepC = (c == NCHUNK - 1) && (ro >= 7);
            V_X[cvaX] = keepC ? cvX : e;
        }
        cvaX += WMAX; if (cvaX >= climC) cvaX -= tauC;
        __syncthreads();                                     // B8 (V_X complete)
    }

    // ---- per-stream argmax over own quarter V; publish result + sentinel ----
    for (int st = 0; st < 2; ++st) {
        const float* VS = st ? V_Y : V_X;
        float bvv = -INFINITY; int bss = 0x7fffffff;
        for (int g = tid; g < sv; g += NTHREADS) {
            int lo = 0, hi = nq - 1;
            while (lo < hi) { int mid = (lo + hi + 1) >> 1;
                              if (mid * (TMIN + q) + 2 * mid * (mid - 1) <= g) lo = mid; else hi = mid - 1; }
            const int r   = g - (lo * (TMIN + q) + 2 * lo * (lo - 1));
            const int tau = TMIN + q + 4 * lo;
            const int j   = q + 4 * lo;
            const int p   = (5998 - r) % tau;
            const int s   = first_of(j) + p;
            const float v = VS[g];
            if (v > bvv || (v == bvv && s < bss)) { bvv = v; bss = s; }
        }
#pragma unroll
        for (int d = 1; d < 64; d <<= 1) {
            const float ov = __shfl_xor(bvv, d);
            const int   os = __shfl_xor(bss, d);
            if (ov > bvv || (ov == bvv && os < bss)) { bvv = ov; bss = os; }
        }
        if ((tid & 63) == 0) { wv[tid >> 6] = bvv; wi[tid >> 6] = bss; }
        __syncthreads();
        if (tid == 0) {
            float bv = wv[0]; int bs = wi[0];
#pragma unroll
            for (int k = 1; k < 16; ++k)
                if (wv[k] > bv || (wv[k] == bv && wi[k] < bs)) { bv = wv[k]; bs = wi[k]; }
            const int bb = st ? by : bx;
            resv[bb * 4 + q] = bv;
            resi[bb * 4 + q] = bs;
            __hip_atomic_fetch_add(&flags[(bb * 4 + q) * FLAG_STRIDE], 1,
                                   __ATOMIC_RELEASE, __HIP_MEMORY_SCOPE_AGENT);
        }
        __syncthreads();
    }

    // ---- merge + backtrace: q==0 WG handles its X batch, q==1 WG its Y batch --
    const int mb = (q == 0) ? bx : (q == 1) ? by : -1;
    if (mb < 0) return;
    if (tid == 0) {
        const int* f0 = flags + (mb * 4 + 0) * FLAG_STRIDE;
        const int* f1 = flags + (mb * 4 + 1) * FLAG_STRIDE;
        const int* f2 = flags + (mb * 4 + 2) * FLAG_STRIDE;
        const int* f3 = flags + (mb * 4 + 3) * FLAG_STRIDE;
        int guard = 0;
        while (true) {
            const int a0 = __hip_atomic_load(f0, __ATOMIC_RELAXED, __HIP_MEMORY_SCOPE_AGENT);
            const int a1 = __hip_atomic_load(f1, __ATOMIC_RELAXED, __HIP_MEMORY_SCOPE_AGENT);
            const int a2 = __hip_atomic_load(f2, __ATOMIC_RELAXED, __HIP_MEMORY_SCOPE_AGENT);
            const int a3 = __hip_atomic_load(f3, __ATOMIC_RELAXED, __HIP_MEMORY_SCOPE_AGENT);
            if (a0 >= SENT && a1 >= SENT && a2 >= SENT && a3 >= SENT) break;
            __builtin_amdgcn_s_sleep(1);
            if (++guard > (1 << 26)) break;
        }
        __builtin_amdgcn_fence(__ATOMIC_ACQUIRE, "agent");
        float bv = -INFINITY; int bs = 0x7fffffff;
#pragma unroll
        for (int k = 0; k < 4; ++k) {
            const float v = resv[mb * 4 + k];
            const int   s = resi[mb * 4 + k];
            if (v > bv || (v == bv && s < bs)) { bv = v; bs = s; }
        }
        sstate = bs;
    }
    __syncthreads();

    // ---- backtrace: wave 0; A row layout is quarter-grouped columns ----------
    if (tid < 64) {
        const float* AhB = Ah_all + (size_t)mb * (NCHUNK * CHUNK_G);
        const int lane = tid;
        int s = sstate;
        int t = TF - 1;
        for (int guard = 0; guard < 400; ++guard) {
            int lo = 0, hi = NTAU - 1;
            while (lo < hi) { int mid = (lo + hi + 1) >> 1;
                              if (first_of(mid) <= s) lo = mid; else hi = mid - 1; }
            const int j = lo;
            const int p = s - first_of(j);
            const int tb = t - p;
            if (tb < 0) break;
            if (lane == 0) {
                const float x = logit[mb * TF + tb];
                const float act = 1.0f / (1.0f + expf(-x));
                if (act >= 0.05f) out[mb * TF + tb] = 1.0f;
            }
            if (tb == 0) break;
            const int tq = tb - 1;
            const float* arow = AhB + (size_t)(tq / WMAX) * CHUNK_G + (tq % WMAX) * AP;
            float cvv = arow[qpos_of(lane)] + transg[lane * NTAU + j];
            int ci = lane;
            if (lane < NTAU - 64) {
                const int i2 = 64 + lane;
                const float c2 = arow[qpos_of(i2)] + transg[i2 * NTAU + j];
                if (c2 > cvv) { cvv = c2; ci = i2; }
            }
#pragma unroll
            for (int d = 1; d < 64; d <<= 1) {
                const float ov = __shfl_xor(cvv, d, 64);
                const int   oi = __shfl_xor(ci, d, 64);
                if (ov > cvv || (ov == cvv && oi < ci)) { cvv = ov; ci = oi; }
            }
            s = first_of(ci) + (TMIN + ci) - 1;   // last_idx[i*]
            t = tb - 1;
        }
    }
}

extern "C" void kernel_launch(void* const* d_in, const int* in_sizes, int n_in,
                              void* d_out, int out_size, void* d_ws, size_t ws_size,
                              hipStream_t stream) {
    const float* logit = (const float*)d_in[0];
    float* out = (float*)d_out;
    float* ws = (float*)d_ws;
    k_trans<<<dim3(NTAU), dim3(128), 0, stream>>>(ws);
    k_emis<<<dim3((BATCH * TF + 255) / 256), dim3(256), 0, stream>>>(logit, ws, out);
    k_flags<<<dim3(4), dim3(256), 0, stream>>>((int*)(ws + FLAG_OFF));
    k_viterbi<<<dim3(8), dim3(NTHREADS), 0, stream>>>(
        logit, ws + TRANS_OFF, ws + BLP_OFF, ws + NBLP_OFF, ws + AH_OFF,
        (int*)(ws + FLAG_OFF), ws + RESV_OFF, (int*)(ws + RESI_OFF), out);
}